// Round 12
// baseline (41.597 us; speedup 1.0000x reference)
//
#include <hip/hip_runtime.h>
#include <math.h>

#define GAMMA 0.3f      // NUM_BASIS / MAX_RADIUS = 3/10
#define WSTR3 424       // k2 LDS row stride in bf16 (416 = 13 ks x 32 + 8 pad; 848B rows -> 2-way bank alias, free)

typedef __bf16 bf16x8 __attribute__((ext_vector_type(8)));
typedef __bf16 bf16x4 __attribute__((ext_vector_type(4)));
typedef float  f32x4  __attribute__((ext_vector_type(4)));

// ---------------------------------------------------------------------------
// K2: grid 1024 = z(4) x bc(16) x hh(4) x ah(4); 256 threads = 4 waves.
// Block: a in [ah*64,+64), b in [bc*16,+16), h in [hh*25,+25); K = 400.
// 26.5 KB LDS -> 4 blocks/CU -> 16 waves/CU = 4 waves/SIMD (2x round-11).
// Phase B: W[b,h,i] = x·rw2 via MFMA -> LDS bf16 kl-packed (r10/r11-proven):
//   Wlds[icol*WSTR3 + ks*32 + (b>>2)*8 + hpar*4 + (b&3)]; B-frag = 1 ds_read_b128
//   25 h = 12 full k-steps (2h x 16b) + epilogue step (h_loc=24, odd half zeroed).
// Phase C: wave w owns a-tile w; 12 k-steps + epilogue; 2 i-tiles.
// MFMA 16x16x32 bf16 frags: A[m=l&15][k=(l>>4)*4+e, +16]; B[k][n=l&15];
//   D col=l&15, row=(l>>4)*4+r   (learn_hip m89-verified)
// ---------------------------------------------------------------------------
__global__ __launch_bounds__(256, 4) void k2_fused(const float* __restrict__ x,
                                                   const float* __restrict__ xyz,
                                                   const float* __restrict__ rw1,
                                                   const float* __restrict__ rw2,
                                                   float* __restrict__ part) {
    __shared__ __bf16 Wlds[32 * WSTR3];    // 27,136 B
    __shared__ float  rw1s[304];           //  1,216 B

    int bid = blockIdx.x;
    int ah = bid & 3;
    int hh = (bid >> 2) & 3;
    int bc = (bid >> 4) & 15;
    int z  = bid >> 8;
    int t  = threadIdx.x;
    int w  = t >> 6;              // 0..3 = a-tile
    int l  = t & 63;
    int l16 = l & 15, lg = l >> 4;

    for (int e = t; e < 300; e += 256) rw1s[e] = rw1[e];
    // zero-fill the unwritten odd-h half of k-step 12: kl = 12*32 + lg*8 + 4..7
    if (t < 128) {
        int icol = t >> 2, g = t & 3;
        *(bf16x4*)&Wlds[icol * WSTR3 + 12 * 32 + g * 8 + 4] = (bf16x4){(__bf16)0.f, (__bf16)0.f, (__bf16)0.f, (__bf16)0.f};
    }

    // ---- phase A: per-lane bas registers: a = l16 of wave's a-tile, b = lg*4+e ----
    int a_glob = ah * 64 + w * 16 + l16;
    float ax = xyz[(z * 256 + a_glob) * 3 + 0];
    float ay = xyz[(z * 256 + a_glob) * 3 + 1];
    float az = xyz[(z * 256 + a_glob) * 3 + 2];
    float bas[4][3];
    #pragma unroll
    for (int e = 0; e < 4; ++e) {
        int b_glob = bc * 16 + lg * 4 + e;
        float dx = xyz[(z * 256 + b_glob) * 3 + 0] - ax;
        float dy = xyz[(z * 256 + b_glob) * 3 + 1] - ay;
        float dz = xyz[(z * 256 + b_glob) * 3 + 2] - az;
        float r  = sqrtf(dx * dx + dy * dy + dz * dz + 1e-12f);
        float r5 = r - 5.f, r10 = r - 10.f;
        bas[e][0] = __expf(-GAMMA * r * r);
        bas[e][1] = __expf(-GAMMA * r5 * r5);
        bas[e][2] = __expf(-GAMMA * r10 * r10);
    }

    // ---- phase B: W slice via MFMA; 50 n-tiles (25 h x 2 i-tiles) over 4 waves ----
    bf16x8 xa;
    {
        int row = (z * 256 + bc * 16 + l16) * 32;
        float4 v0 = *(const float4*)(x + row + lg * 4);
        float4 v1 = *(const float4*)(x + row + lg * 4 + 16);
        xa[0] = (__bf16)v0.x; xa[1] = (__bf16)v0.y; xa[2] = (__bf16)v0.z; xa[3] = (__bf16)v0.w;
        xa[4] = (__bf16)v1.x; xa[5] = (__bf16)v1.y; xa[6] = (__bf16)v1.z; xa[7] = (__bf16)v1.w;
    }
    for (int q = 0; q < 13; ++q) {
        int nt = q * 4 + w;                  // 0..51; valid < 50
        if (nt < 50) {
            int h_loc = nt >> 1;             // 0..24
            int h = hh * 25 + h_loc;
            int ks = h_loc >> 1, hpar = h_loc & 1;
            int icol = ((nt & 1) << 4) + l16;
            const float* rp = rw2 + h * 1024 + icol * 32 + lg * 4;
            float4 r0 = *(const float4*)rp;
            float4 r1 = *(const float4*)(rp + 16);
            bf16x8 rb;
            rb[0] = (__bf16)r0.x; rb[1] = (__bf16)r0.y; rb[2] = (__bf16)r0.z; rb[3] = (__bf16)r0.w;
            rb[4] = (__bf16)r1.x; rb[5] = (__bf16)r1.y; rb[6] = (__bf16)r1.z; rb[7] = (__bf16)r1.w;
            f32x4 d = {0.f, 0.f, 0.f, 0.f};
            d = __builtin_amdgcn_mfma_f32_16x16x32_bf16(xa, rb, d, 0, 0, 0);
            bf16x4 pk;
            pk[0] = (__bf16)d[0]; pk[1] = (__bf16)d[1]; pk[2] = (__bf16)d[2]; pk[3] = (__bf16)d[3];
            *(bf16x4*)&Wlds[icol * WSTR3 + ks * 32 + lg * 8 + hpar * 4] = pk;
        }
    }
    __syncthreads();

    // ---- phase C: 12 full k-steps (2h x 16b) + epilogue (h_loc=24) ----
    f32x4 acc0 = {0.f, 0.f, 0.f, 0.f};
    f32x4 acc1 = {0.f, 0.f, 0.f, 0.f};
    for (int ks = 0; ks < 12; ++ks) {
        int h0 = hh * 25 + 2 * ks;
        float u00 = rw1s[h0],       u01 = rw1s[h0 + 1];
        float u10 = rw1s[100 + h0], u11 = rw1s[101 + h0];
        float u20 = rw1s[200 + h0], u21 = rw1s[201 + h0];
        bf16x8 af;
        #pragma unroll
        for (int e = 0; e < 4; ++e) {
            float p0 = bas[e][0] * u00 + bas[e][1] * u10 + bas[e][2] * u20;
            float p1 = bas[e][0] * u01 + bas[e][1] * u11 + bas[e][2] * u21;
            float s0 = p0 * __builtin_amdgcn_rcpf(1.f + __expf(-p0));   // swish
            float s1 = p1 * __builtin_amdgcn_rcpf(1.f + __expf(-p1));
            af[e]     = (__bf16)s0;    // k = lg*4+e      (h0, even)
            af[e + 4] = (__bf16)s1;    // k = lg*4+e+16   (h1, odd)
        }
        int kb = ks * 32 + lg * 8;
        bf16x8 bf0 = *(const bf16x8*)&Wlds[l16 * WSTR3 + kb];
        bf16x8 bf1 = *(const bf16x8*)&Wlds[(16 + l16) * WSTR3 + kb];
        acc0 = __builtin_amdgcn_mfma_f32_16x16x32_bf16(af, bf0, acc0, 0, 0, 0);
        acc1 = __builtin_amdgcn_mfma_f32_16x16x32_bf16(af, bf1, acc1, 0, 0, 0);
    }
    {   // epilogue: h_loc = 24 only; odd half zero on both A and B sides
        int h0 = hh * 25 + 24;
        float u00 = rw1s[h0], u10 = rw1s[100 + h0], u20 = rw1s[200 + h0];
        bf16x8 af;
        #pragma unroll
        for (int e = 0; e < 4; ++e) {
            float p0 = bas[e][0] * u00 + bas[e][1] * u10 + bas[e][2] * u20;
            float s0 = p0 * __builtin_amdgcn_rcpf(1.f + __expf(-p0));
            af[e]     = (__bf16)s0;
            af[e + 4] = (__bf16)0.f;
        }
        int kb = 12 * 32 + lg * 8;
        bf16x8 bf0 = *(const bf16x8*)&Wlds[l16 * WSTR3 + kb];
        bf16x8 bf1 = *(const bf16x8*)&Wlds[(16 + l16) * WSTR3 + kb];
        acc0 = __builtin_amdgcn_mfma_f32_16x16x32_bf16(af, bf0, acc0, 0, 0, 0);
        acc1 = __builtin_amdgcn_mfma_f32_16x16x32_bf16(af, bf1, acc1, 0, 0, 0);
    }

    // ---- write partials: chunk qc = bc*4+hh; D row r -> a = atile + lg*4+r ----
    int qc = bc * 4 + hh;
    #pragma unroll
    for (int r = 0; r < 4; ++r) {
        int a = ah * 64 + w * 16 + lg * 4 + r;
        size_t base = ((size_t)(z * 64 + qc) * 256 + a) * 32;
        part[base + l16]      = acc0[r];
        part[base + 16 + l16] = acc1[r];
    }
}

// ---------------------------------------------------------------------------
// K3a (r5-proven): sum over 64 chunks, abs+mask+scale, pool 4 a's per block.
// grid: 256 blocks = z(4) x ag(64); 256 threads = a_loc(4) x qg(2) x i(32)
// ---------------------------------------------------------------------------
__global__ __launch_bounds__(256) void k3a_reduce(const float* __restrict__ part,
                                                  const int* __restrict__ mask,
                                                  float* __restrict__ pooled_part) {
    int blk = blockIdx.x;
    int z = blk >> 6, ag = blk & 63;
    int t = threadIdx.x;
    int i = t & 31;
    int qg = (t >> 5) & 1;
    int a_loc = t >> 6;               // 0..3
    int a = ag * 4 + a_loc;
    const float* base = part + ((size_t)z * 64 * 256 + (size_t)a) * 32 + i;
    float s = 0.f;
    for (int q = qg; q < 64; q += 2)
        s += base[(size_t)q * 8192];
    __shared__ float buf[4][2][32];
    buf[a_loc][qg][i] = s;
    __syncthreads();
    if (t < 128) {
        int al = t >> 5, ii = t & 31;
        float v = buf[al][0][ii] + buf[al][1][ii];
        float sc = (mask[z * 256 + ag * 4 + al] != 0) ? 0.0625f : 0.f;   // 1/sqrt(256)
        buf[al][0][ii] = fabsf(v) * sc;
    }
    __syncthreads();
    if (t < 32) {
        float v = buf[0][0][t] + buf[1][0][t] + buf[2][0][t] + buf[3][0][t];
        pooled_part[(z * 64 + ag) * 32 + t] = v;
    }
}

// ---------------------------------------------------------------------------
// K3b (r5-proven): pool over ag(64), normalize (ddof=1), fc3+leaky, fc2 -> out
// ---------------------------------------------------------------------------
__global__ __launch_bounds__(128) void k3b_final(const float* __restrict__ pooled_part,
                                                 const float* __restrict__ fc3_w,
                                                 const float* __restrict__ fc3_b,
                                                 const float* __restrict__ fc2_w,
                                                 const float* __restrict__ fc2_b,
                                                 float* __restrict__ out) {
    int t = threadIdx.x;
    int z = t >> 5, i = t & 31;
    float s = 0.f;
    for (int ag = 0; ag < 64; ++ag) s += pooled_part[(z * 64 + ag) * 32 + i];
    float sm = s;
    #pragma unroll
    for (int off = 16; off; off >>= 1) sm += __shfl_xor(sm, off, 32);
    float mean = sm * (1.f / 32.f);
    float d = s - mean;
    float ss = d * d;
    #pragma unroll
    for (int off = 16; off; off >>= 1) ss += __shfl_xor(ss, off, 32);
    float stdv = sqrtf(ss * (1.f / 31.f));   // ddof=1
    float nv = d / (stdv + 1e-6f);
    __shared__ float pn[4][32];
    pn[z][i] = nv;
    __syncthreads();
    float h1 = fc3_b[i];
    #pragma unroll
    for (int j = 0; j < 32; ++j) h1 += pn[z][j] * fc3_w[j * 32 + i];
    h1 = (h1 >= 0.f) ? h1 : 0.01f * h1;
    float y = h1 * fc2_w[i];
    #pragma unroll
    for (int off = 16; off; off >>= 1) y += __shfl_xor(y, off, 32);
    if (i == 0) out[z] = y + fc2_b[0];
}

extern "C" void kernel_launch(void* const* d_in, const int* in_sizes, int n_in,
                              void* d_out, int out_size, void* d_ws, size_t ws_size,
                              hipStream_t stream) {
    const float* x    = (const float*)d_in[0];
    const float* xyz  = (const float*)d_in[1];
    const int*   mask = (const int*)d_in[2];
    const float* rw1  = (const float*)d_in[3];
    const float* rw2  = (const float*)d_in[4];
    const float* fc3w = (const float*)d_in[5];
    const float* fc3b = (const float*)d_in[6];
    const float* fc2w = (const float*)d_in[7];
    const float* fc2b = (const float*)d_in[8];
    float* out = (float*)d_out;

    float* part        = (float*)d_ws;                     // 4z*64qc*256a*32i*4B = 8,388,608 B
    float* pooled_part = (float*)((char*)d_ws + 8388608);  // 32,768 B

    hipLaunchKernelGGL(k2_fused,   dim3(1024), dim3(256), 0, stream, x, xyz, rw1, rw2, part);
    hipLaunchKernelGGL(k3a_reduce, dim3(256),  dim3(256), 0, stream, part, mask, pooled_part);
    hipLaunchKernelGGL(k3b_final,  dim3(1),    dim3(128), 0, stream, pooled_part, fc3w, fc3b, fc2w, fc2b, out);
}